// Round 5
// baseline (670.580 us; speedup 1.0000x reference)
//
#include <hip/hip_runtime.h>
#include <cstdint>
#include <cstddef>

// GIN 3-layer + BN + mean-pool. R5: fully fused per-layer kernel
// (gather-agg -> MLP1 -> MLP2 -> BN stats) with LDS-resident intermediates.
// 80 KB LDS/block -> 2 blocks/CU so gather (memory) overlaps MFMA (compute).

constexpr int N_NODES  = 50000;
constexpr int N_EDGES  = 800000;
constexpr int F_IN     = 128;
constexpr int HID      = 256;
constexpr int N_GRAPHS = 512;
constexpr float BN_EPS = 1e-5f;

constexpr int SCAN_CHUNK = 4096;
constexpr int SCAN_NB    = (N_NODES + SCAN_CHUNK - 1) / SCAN_CHUNK; // 13

typedef unsigned short u16;
typedef u16 u16x4 __attribute__((ext_vector_type(4)));
typedef u16 u16x8 __attribute__((ext_vector_type(8)));
typedef __bf16 bf16x8 __attribute__((ext_vector_type(8)));
typedef float f32x4 __attribute__((ext_vector_type(4)));

__device__ __forceinline__ u16 f2bf(float f) {
    uint32_t u = __float_as_uint(f);
    uint32_t r = (u + 0x7FFFu + ((u >> 16) & 1u)) >> 16;
    return (u16)r;
}
__device__ __forceinline__ float bf2f(u16 h) {
    return __uint_as_float(((uint32_t)h) << 16);
}

// ---------------- x -> bf16 ----------------
__global__ void f2bf_k(const float* __restrict__ in, u16* __restrict__ outp, int n8) {
    int i = blockIdx.x * 256 + threadIdx.x;
    if (i >= n8) return;
    float4 a = reinterpret_cast<const float4*>(in)[i * 2];
    float4 b = reinterpret_cast<const float4*>(in)[i * 2 + 1];
    u16x8 v;
    v[0] = f2bf(a.x); v[1] = f2bf(a.y); v[2] = f2bf(a.z); v[3] = f2bf(a.w);
    v[4] = f2bf(b.x); v[5] = f2bf(b.y); v[6] = f2bf(b.z); v[7] = f2bf(b.w);
    reinterpret_cast<u16x8*>(outp)[i] = v;
}

// ---------------- CSR build ----------------
__global__ void hist_k(const int* __restrict__ dst, int* __restrict__ deg) {
    int e = blockIdx.x * 256 + threadIdx.x;
    if (e < N_EDGES) atomicAdd(&deg[dst[e]], 1);
}

__global__ void scan_part1(const int* __restrict__ in, int* __restrict__ bsum) {
    __shared__ int sm[256];
    int t = threadIdx.x;
    int base = blockIdx.x * SCAN_CHUNK + t * 16;
    int s = 0;
#pragma unroll
    for (int j = 0; j < 16; j++) { int idx = base + j; s += (idx < N_NODES) ? in[idx] : 0; }
    sm[t] = s; __syncthreads();
    for (int off = 128; off > 0; off >>= 1) {
        if (t < off) sm[t] += sm[t + off];
        __syncthreads();
    }
    if (t == 0) bsum[blockIdx.x] = sm[0];
}

__global__ void scan_tops(int* __restrict__ bsum, int* __restrict__ rowptr) {
    if (threadIdx.x == 0 && blockIdx.x == 0) {
        int acc = 0;
        for (int i = 0; i < SCAN_NB; i++) { int v = bsum[i]; bsum[i] = acc; acc += v; }
        rowptr[N_NODES] = acc; // == N_EDGES
    }
}

__global__ void scan_final(const int* __restrict__ in, const int* __restrict__ bsum,
                           int* __restrict__ rowptr, int* __restrict__ cursor) {
    __shared__ int sm[256];
    int t = threadIdx.x;
    int base = blockIdx.x * SCAN_CHUNK + t * 16;
    int loc[16]; int s = 0;
#pragma unroll
    for (int j = 0; j < 16; j++) { int idx = base + j; loc[j] = s; s += (idx < N_NODES) ? in[idx] : 0; }
    sm[t] = s; __syncthreads();
    for (int off = 1; off < 256; off <<= 1) {
        int v = (t >= off) ? sm[t - off] : 0;
        __syncthreads();
        sm[t] += v;
        __syncthreads();
    }
    int excl = sm[t] - s + bsum[blockIdx.x];
#pragma unroll
    for (int j = 0; j < 16; j++) {
        int idx = base + j;
        if (idx < N_NODES) { int rp = excl + loc[j]; rowptr[idx] = rp; cursor[idx] = rp; }
    }
}

__global__ void build_csr(const int* __restrict__ src, const int* __restrict__ dst,
                          int* __restrict__ cursor, int* __restrict__ col) {
    int e = blockIdx.x * 256 + threadIdx.x;
    if (e < N_EDGES) {
        int d = dst[e];
        int p = atomicAdd(&cursor[d], 1);
        col[p] = src[e];
    }
}

// ------- W pre-transpose + bf16 split, all 6 weights in one kernel -------
// Wt[n][k] = hi/lo(W[k][n]); region offsets match launch-side table.
__global__ void wsplit_all(const float* __restrict__ w1a, const float* __restrict__ w2a,
                           const float* __restrict__ w1s, const float* __restrict__ w2s,
                           u16* __restrict__ th, u16* __restrict__ tl) {
    int idx = blockIdx.x * 256 + threadIdx.x;
    const float* W; int K; int local; size_t dof;
    if (idx < 32768)       { W = w1a;         K = 128; local = idx;          dof = 0; }
    else if (idx < 98304)  { W = w2a;         K = 256; local = idx - 32768;  dof = 32768; }
    else if (idx < 163840) { W = w1s;         K = 256; local = idx - 98304;  dof = 98304; }
    else if (idx < 229376) { W = w1s + 65536; K = 256; local = idx - 163840; dof = 163840; }
    else if (idx < 294912) { W = w2s;         K = 256; local = idx - 229376; dof = 229376; }
    else if (idx < 360448) { W = w2s + 65536; K = 256; local = idx - 294912; dof = 294912; }
    else return;
    int n = local & 255, k = local >> 8;
    float f = W[(size_t)k * 256 + n];
    u16 h = f2bf(f);
    th[dof + (size_t)n * K + k] = h;
    tl[dof + (size_t)n * K + k] = f2bf(f - bf2f(h));
}

// ---------------- fused layer kernel ----------------
// Az LDS layout: [row][16B-unit u' = u ^ (row&7)], row stride KK*2 bytes.
// Wb LDS layout: [n][unit uo = j ^ ((n>>1)&3)], row stride 64 bytes.
template <int KK>
__device__ __forceinline__ void gemm_phase(const u16* __restrict__ Wh,
                                           const u16* __restrict__ Wl,
                                           u16* Az, u16* Wb,
                                           int tid, int wm, int wn, int l15, int kg,
                                           f32x4 (&acc)[4][8]) {
#pragma unroll 1
    for (int plane = 0; plane < 2; ++plane) {
        const u16* wsrc = plane ? Wl : Wh;
#pragma unroll 1
        for (int k0 = 0; k0 < KK; k0 += 32) {
            // stage W tile [256 n][32 k]
            const u16* wp = wsrc + (size_t)tid * KK + k0;
#pragma unroll
            for (int j = 0; j < 4; j++) {
                u16x8 v = *reinterpret_cast<const u16x8*>(wp + j * 8);
                int uo = j ^ ((tid >> 1) & 3);
                *reinterpret_cast<u16x8*>((char*)Wb + tid * 64 + uo * 16) = v;
            }
            __syncthreads();
            bf16x8 ah[4];
#pragma unroll
            for (int mi = 0; mi < 4; mi++) {
                int r = wm * 64 + mi * 16 + l15;
                int u = (k0 >> 3) + kg;
                int us = u ^ (r & 7);
                ah[mi] = __builtin_bit_cast(bf16x8,
                    *reinterpret_cast<const u16x8*>((const char*)Az + r * (KK * 2) + us * 16));
            }
#pragma unroll
            for (int ni = 0; ni < 8; ni++) {
                int n = wn * 128 + ni * 16 + l15;
                int uo = kg ^ ((n >> 1) & 3);
                bf16x8 b = __builtin_bit_cast(bf16x8,
                    *reinterpret_cast<const u16x8*>((const char*)Wb + n * 64 + uo * 16));
#pragma unroll
                for (int mi = 0; mi < 4; mi++)
                    acc[mi][ni] = __builtin_amdgcn_mfma_f32_16x16x32_bf16(ah[mi], b, acc[mi][ni], 0, 0, 0);
            }
            __syncthreads();
        }
    }
}

// One GIN layer: out = bf16(relu(relu(FOLD(agg(Hin)) @ W1 + b1) @ W2 + b2)), + BN stats.
template <int K1, bool FOLD>
__global__ __launch_bounds__(256, 2) void layer_k(const u16* __restrict__ Hin,
                                                  const int* __restrict__ rowptr,
                                                  const int* __restrict__ colidx,
                                                  const float* __restrict__ scsh,
                                                  const u16* __restrict__ W1h,
                                                  const u16* __restrict__ W1l,
                                                  const float* __restrict__ b1,
                                                  const u16* __restrict__ W2h,
                                                  const u16* __restrict__ W2l,
                                                  const float* __restrict__ b2,
                                                  u16* __restrict__ Out,
                                                  float* __restrict__ stats) {
    constexpr int BM = 128;
    __shared__ alignas(16) u16 Az[BM * 256];   // 64 KB (z buffer; layer-1 agg uses half)
    __shared__ alignas(16) u16 Wb[256 * 32];   // 16 KB (W stage; aliased by stats in epilogue)
    float* smsum = reinterpret_cast<float*>(Wb);
    float* smsq  = reinterpret_cast<float*>(Wb) + 256;

    const int tid  = threadIdx.x;
    const int r0   = blockIdx.x * BM;
    const int lane = tid & 63, wid = tid >> 6;
    const int wm = wid >> 1, wn = wid & 1;
    const int l15 = lane & 15, kg = lane >> 4;

    // ---------- phase 0: gather-aggregate into Az (bf16, swizzled) ----------
    if constexpr (K1 == 256) {
        const u16x4* hp = reinterpret_cast<const u16x4*>(Hin); // 64 units/row
        float4 sc, sh;
        if constexpr (FOLD) {
            sc = *reinterpret_cast<const float4*>(&scsh[lane * 4]);
            sh = *reinterpret_cast<const float4*>(&scsh[256 + lane * 4]);
        }
#pragma unroll 1
        for (int it = 0; it < 32; ++it) {          // one row per wave
            int rloc = it * 4 + wid;
            int node = r0 + rloc;
            float a[4] = {};
            if (node < N_NODES) {
                int beg = rowptr[node], end = rowptr[node + 1];
                u16x4 sv = hp[(size_t)node * 64 + lane];
#pragma unroll
                for (int i = 0; i < 4; i++) a[i] = bf2f(sv[i]);
                int e = beg;
                for (; e + 4 <= end; e += 4) {
                    int s0 = colidx[e], s1 = colidx[e + 1], s2 = colidx[e + 2], s3 = colidx[e + 3];
                    u16x4 v0 = hp[(size_t)s0 * 64 + lane];
                    u16x4 v1 = hp[(size_t)s1 * 64 + lane];
                    u16x4 v2 = hp[(size_t)s2 * 64 + lane];
                    u16x4 v3 = hp[(size_t)s3 * 64 + lane];
#pragma unroll
                    for (int i = 0; i < 4; i++)
                        a[i] += (bf2f(v0[i]) + bf2f(v1[i])) + (bf2f(v2[i]) + bf2f(v3[i]));
                }
                for (; e < end; ++e) {
                    u16x4 v = hp[(size_t)colidx[e] * 64 + lane];
#pragma unroll
                    for (int i = 0; i < 4; i++) a[i] += bf2f(v[i]);
                }
                if constexpr (FOLD) {
                    float m = (float)(end - beg + 1);
                    a[0] = a[0] * sc.x + m * sh.x;
                    a[1] = a[1] * sc.y + m * sh.y;
                    a[2] = a[2] * sc.z + m * sh.z;
                    a[3] = a[3] * sc.w + m * sh.w;
                }
            }
            u16x4 rv;
#pragma unroll
            for (int i = 0; i < 4; i++) rv[i] = f2bf(a[i]);
            int us = (lane >> 1) ^ (rloc & 7);
            *reinterpret_cast<u16x4*>((char*)Az + rloc * 512 + us * 16 + (lane & 1) * 8) = rv;
        }
    } else {  // K1 == 128: half-wave per row
        const u16x4* hp = reinterpret_cast<const u16x4*>(Hin); // 32 units/row
        int hw = tid >> 5, hl = tid & 31;
#pragma unroll 1
        for (int it = 0; it < 16; ++it) {
            int rloc = it * 8 + hw;
            int node = r0 + rloc;
            float a[4] = {};
            if (node < N_NODES) {
                int beg = rowptr[node], end = rowptr[node + 1];
                u16x4 sv = hp[(size_t)node * 32 + hl];
#pragma unroll
                for (int i = 0; i < 4; i++) a[i] = bf2f(sv[i]);
                int e = beg;
                for (; e + 4 <= end; e += 4) {
                    int s0 = colidx[e], s1 = colidx[e + 1], s2 = colidx[e + 2], s3 = colidx[e + 3];
                    u16x4 v0 = hp[(size_t)s0 * 32 + hl];
                    u16x4 v1 = hp[(size_t)s1 * 32 + hl];
                    u16x4 v2 = hp[(size_t)s2 * 32 + hl];
                    u16x4 v3 = hp[(size_t)s3 * 32 + hl];
#pragma unroll
                    for (int i = 0; i < 4; i++)
                        a[i] += (bf2f(v0[i]) + bf2f(v1[i])) + (bf2f(v2[i]) + bf2f(v3[i]));
                }
                for (; e < end; ++e) {
                    u16x4 v = hp[(size_t)colidx[e] * 32 + hl];
#pragma unroll
                    for (int i = 0; i < 4; i++) a[i] += bf2f(v[i]);
                }
            }
            u16x4 rv;
#pragma unroll
            for (int i = 0; i < 4; i++) rv[i] = f2bf(a[i]);
            int us = (hl >> 1) ^ (rloc & 7);
            *reinterpret_cast<u16x4*>((char*)Az + rloc * 256 + us * 16 + (hl & 1) * 8) = rv;
        }
    }
    // no explicit barrier needed: gemm_phase's first staging barrier covers Az writes

    // ---------- phase 1: z1 = relu(Az @ W1 + b1) ----------
    f32x4 acc[4][8];
#pragma unroll
    for (int i = 0; i < 4; i++)
#pragma unroll
        for (int j = 0; j < 8; j++) acc[i][j] = (f32x4){0.f, 0.f, 0.f, 0.f};
    gemm_phase<K1>(W1h, W1l, Az, Wb, tid, wm, wn, l15, kg, acc);

    // write z1 into Az (bf16, stride 512, swizzled); ends with barrier
    {
        float bv[8];
#pragma unroll
        for (int ni = 0; ni < 8; ni++) bv[ni] = b1[wn * 128 + ni * 16 + l15];
#pragma unroll
        for (int mi = 0; mi < 4; mi++) {
#pragma unroll
            for (int rr = 0; rr < 4; rr++) {
                int r = wm * 64 + mi * 16 + kg * 4 + rr;
#pragma unroll
                for (int ni = 0; ni < 8; ni++) {
                    float v = fmaxf(acc[mi][ni][rr] + bv[ni], 0.f);
                    int c = wn * 128 + ni * 16 + l15;
                    int us = (c >> 3) ^ (r & 7);
                    reinterpret_cast<u16*>((char*)Az + r * 512 + us * 16)[c & 7] = f2bf(v);
                }
            }
        }
        __syncthreads();
    }

    // ---------- phase 2: z2 = relu(z1 @ W2 + b2) ----------
#pragma unroll
    for (int i = 0; i < 4; i++)
#pragma unroll
        for (int j = 0; j < 8; j++) acc[i][j] = (f32x4){0.f, 0.f, 0.f, 0.f};
    gemm_phase<256>(W2h, W2l, Az, Wb, tid, wm, wn, l15, kg, acc);

    // ---------- epilogue: bias + relu + bf16 store + BN stats ----------
    smsum[tid] = 0.f;   // aliases Wb; safe: gemm_phase ended with barrier
    smsq[tid]  = 0.f;
    __syncthreads();
    float bv[8];
#pragma unroll
    for (int ni = 0; ni < 8; ni++) bv[ni] = b2[wn * 128 + ni * 16 + l15];
    float ps[8] = {}, pq[8] = {};
#pragma unroll
    for (int mi = 0; mi < 4; mi++) {
        int rowb = r0 + wm * 64 + mi * 16 + kg * 4;
#pragma unroll
        for (int rr = 0; rr < 4; rr++) {
            int row = rowb + rr;
            if (row < N_NODES) {
                u16* cp = Out + (size_t)row * HID + wn * 128 + l15;
#pragma unroll
                for (int ni = 0; ni < 8; ni++) {
                    float v = fmaxf(acc[mi][ni][rr] + bv[ni], 0.f);
                    cp[ni * 16] = f2bf(v);
                    ps[ni] += v; pq[ni] += v * v;
                }
            }
        }
    }
#pragma unroll
    for (int ni = 0; ni < 8; ni++) {
        int c = wn * 128 + ni * 16 + l15;
        atomicAdd(&smsum[c], ps[ni]);
        atomicAdd(&smsq[c], pq[ni]);
    }
    __syncthreads();
    atomicAdd(&stats[tid], smsum[tid]);
    atomicAdd(&stats[HID + tid], smsq[tid]);
}

// ---------------- BN finalize: stats -> scale/shift ----------------
__global__ void bn_finalize(const float* __restrict__ stats, const float* __restrict__ gamma,
                            const float* __restrict__ beta, float* __restrict__ scsh) {
    int c = threadIdx.x;
    float mu  = stats[c] * (1.f / N_NODES);
    float var = stats[HID + c] * (1.f / N_NODES) - mu * mu;
    float g = gamma[c] * rsqrtf(var + BN_EPS);
    scsh[c] = g;
    scsh[HID + c] = beta[c] - mu * g;
}

// ---------------- mean pool (batch sorted), layer-3 BN folded ----------------
__device__ __forceinline__ int lowerb(const int* a, int key) {
    int lo = 0, hi = N_NODES;
    while (lo < hi) { int mid = (lo + hi) >> 1; if (a[mid] < key) lo = mid + 1; else hi = mid; }
    return lo;
}

__global__ void pool_k(const u16* __restrict__ h, const int* __restrict__ batch,
                       const float* __restrict__ scsh, float* __restrict__ out) {
    __shared__ int bnd[2];
    int g = blockIdx.x;
    if (threadIdx.x == 0) bnd[0] = lowerb(batch, g);
    if (threadIdx.x == 1) bnd[1] = lowerb(batch, g + 1);
    __syncthreads();
    int lo = bnd[0], hi = bnd[1];
    int c = threadIdx.x;
    float s = 0.f;
    for (int r = lo; r < hi; ++r) s += bf2f(h[(size_t)r * HID + c]);
    int cnt = hi - lo;
    float v = (cnt > 0) ? (scsh[c] * (s / (float)cnt) + scsh[HID + c]) : 0.f;
    out[(size_t)g * HID + c] = v;
}

// ---------------- launch ----------------
extern "C" void kernel_launch(void* const* d_in, const int* in_sizes, int n_in,
                              void* d_out, int out_size, void* d_ws, size_t ws_size,
                              hipStream_t stream) {
    const float* x   = (const float*)d_in[0];
    const int*   ei  = (const int*)d_in[1];
    const int* batch = (const int*)d_in[2];
    const float* w1a = (const float*)d_in[3];
    const float* b1a = (const float*)d_in[4];
    const float* w2a = (const float*)d_in[5];
    const float* b2a = (const float*)d_in[6];
    const float* ga  = (const float*)d_in[7];
    const float* ba  = (const float*)d_in[8];
    const float* w1s = (const float*)d_in[9];
    const float* b1s = (const float*)d_in[10];
    const float* w2s = (const float*)d_in[11];
    const float* b2s = (const float*)d_in[12];
    const float* gs  = (const float*)d_in[13];
    const float* bs  = (const float*)d_in[14];
    const int* src = ei;
    const int* dst = ei + N_EDGES;

    char* ws = (char*)d_ws;
    size_t off = 0;
    auto alloc = [&](size_t bytes) { void* p = ws + off; off += (bytes + 255) & ~(size_t)255; return p; };
    u16* A      = (u16*)alloc(sizeof(u16) * (size_t)N_NODES * HID);
    u16* B      = (u16*)alloc(sizeof(u16) * (size_t)N_NODES * HID);
    u16* Xb     = (u16*)alloc(sizeof(u16) * (size_t)N_NODES * F_IN);
    int* rowptr = (int*)alloc(sizeof(int) * (N_NODES + 1));
    int* deg    = (int*)alloc(sizeof(int) * N_NODES);
    int* cursor = (int*)alloc(sizeof(int) * N_NODES);
    int* col    = (int*)alloc(sizeof(int) * N_EDGES);
    int* bsum   = (int*)alloc(sizeof(int) * 64);
    float* stats  = (float*)alloc(sizeof(float) * 512 * 3);  // sum||sq per layer
    float* scsh   = (float*)alloc(sizeof(float) * 512 * 3);  // scale||shift per layer
    constexpr size_t WT_TOT = 32768 + 5 * 65536;
    u16* WtH = (u16*)alloc(sizeof(u16) * WT_TOT);
    u16* WtL = (u16*)alloc(sizeof(u16) * WT_TOT);
    constexpr size_t o1a = 0, o2a = 32768, o1s0 = 98304, o1s1 = 163840, o2s0 = 229376, o2s1 = 294912;
    float* out    = (float*)d_out;
    (void)ws_size; (void)in_sizes; (void)n_in; (void)out_size;

    // ---- input/weight prep ----
    f2bf_k<<<(N_NODES * F_IN / 8 + 255) / 256, 256, 0, stream>>>(x, Xb, N_NODES * F_IN / 8);
    wsplit_all<<<(360448 + 255) / 256, 256, 0, stream>>>(w1a, w2a, w1s, w2s, WtH, WtL);
    hipMemsetAsync(stats, 0, sizeof(float) * 512 * 3, stream);

    // ---- CSR build (by dst) ----
    hipMemsetAsync(deg, 0, sizeof(int) * N_NODES, stream);
    hist_k<<<N_EDGES / 256, 256, 0, stream>>>(dst, deg);
    scan_part1<<<SCAN_NB, 256, 0, stream>>>(deg, bsum);
    scan_tops<<<1, 64, 0, stream>>>(bsum, rowptr);
    scan_final<<<SCAN_NB, 256, 0, stream>>>(deg, bsum, rowptr, cursor);
    build_csr<<<N_EDGES / 256, 256, 0, stream>>>(src, dst, cursor, col);

    const int LAYER_GRID = (N_NODES + 127) / 128; // 391

    // ---- layer 1 ----
    layer_k<128, false><<<LAYER_GRID, 256, 0, stream>>>(
        Xb, rowptr, col, nullptr,
        WtH + o1a, WtL + o1a, b1a, WtH + o2a, WtL + o2a, b2a, B, stats);
    bn_finalize<<<1, 256, 0, stream>>>(stats, ga, ba, scsh);

    // ---- layer 2 (BN1 folded into aggregate) ----
    layer_k<256, true><<<LAYER_GRID, 256, 0, stream>>>(
        B, rowptr, col, scsh,
        WtH + o1s0, WtL + o1s0, b1s, WtH + o2s0, WtL + o2s0, b2s, A, stats + 512);
    bn_finalize<<<1, 256, 0, stream>>>(stats + 512, gs, bs, scsh + 512);

    // ---- layer 3 (BN2 folded into aggregate) ----
    layer_k<256, true><<<LAYER_GRID, 256, 0, stream>>>(
        A, rowptr, col, scsh + 512,
        WtH + o1s1, WtL + o1s1, b1s + 256, WtH + o2s1, WtL + o2s1, b2s + 256, B, stats + 1024);
    bn_finalize<<<1, 256, 0, stream>>>(stats + 1024, gs + 256, bs + 256, scsh + 1024);

    // ---- pool (BN3 folded in) ----
    pool_k<<<N_GRAPHS, 256, 0, stream>>>(B, batch, scsh + 1024, out);
}

// Round 6
// 622.873 us; speedup vs baseline: 1.0766x; 1.0766x over previous
//
#include <hip/hip_runtime.h>
#include <cstdint>
#include <cstddef>

// GIN 3-layer + BN + mean-pool. R6: R4 structure (separate kernels) +
// XCD-sliced L2-resident gather aggregation (slice = blockIdx%8 -> one XCD's L2).

constexpr int N_NODES  = 50000;
constexpr int N_EDGES  = 800000;
constexpr int F_IN     = 128;
constexpr int HID      = 256;
constexpr int N_GRAPHS = 512;
constexpr float BN_EPS = 1e-5f;

constexpr int SCAN_CHUNK = 4096;
constexpr int SCAN_NB    = (N_NODES + SCAN_CHUNK - 1) / SCAN_CHUNK; // 13

typedef unsigned short u16;
typedef u16 u16x2 __attribute__((ext_vector_type(2)));
typedef u16 u16x8 __attribute__((ext_vector_type(8)));
typedef __bf16 bf16x8 __attribute__((ext_vector_type(8)));
typedef float f32x4 __attribute__((ext_vector_type(4)));

__device__ __forceinline__ u16 f2bf(float f) {
    uint32_t u = __float_as_uint(f);
    uint32_t r = (u + 0x7FFFu + ((u >> 16) & 1u)) >> 16;
    return (u16)r;
}
__device__ __forceinline__ float bf2f(u16 h) {
    return __uint_as_float(((uint32_t)h) << 16);
}

// ---------------- CSR build ----------------
__global__ void hist_k(const int* __restrict__ dst, int* __restrict__ deg) {
    int e = blockIdx.x * 256 + threadIdx.x;
    if (e < N_EDGES) atomicAdd(&deg[dst[e]], 1);
}

__global__ void scan_part1(const int* __restrict__ in, int* __restrict__ bsum) {
    __shared__ int sm[256];
    int t = threadIdx.x;
    int base = blockIdx.x * SCAN_CHUNK + t * 16;
    int s = 0;
#pragma unroll
    for (int j = 0; j < 16; j++) { int idx = base + j; s += (idx < N_NODES) ? in[idx] : 0; }
    sm[t] = s; __syncthreads();
    for (int off = 128; off > 0; off >>= 1) {
        if (t < off) sm[t] += sm[t + off];
        __syncthreads();
    }
    if (t == 0) bsum[blockIdx.x] = sm[0];
}

__global__ void scan_tops(int* __restrict__ bsum, int* __restrict__ rowptr) {
    if (threadIdx.x == 0 && blockIdx.x == 0) {
        int acc = 0;
        for (int i = 0; i < SCAN_NB; i++) { int v = bsum[i]; bsum[i] = acc; acc += v; }
        rowptr[N_NODES] = acc; // == N_EDGES
    }
}

__global__ void scan_final(const int* __restrict__ in, const int* __restrict__ bsum,
                           int* __restrict__ rowptr, int* __restrict__ cursor) {
    __shared__ int sm[256];
    int t = threadIdx.x;
    int base = blockIdx.x * SCAN_CHUNK + t * 16;
    int loc[16]; int s = 0;
#pragma unroll
    for (int j = 0; j < 16; j++) { int idx = base + j; loc[j] = s; s += (idx < N_NODES) ? in[idx] : 0; }
    sm[t] = s; __syncthreads();
    for (int off = 1; off < 256; off <<= 1) {
        int v = (t >= off) ? sm[t - off] : 0;
        __syncthreads();
        sm[t] += v;
        __syncthreads();
    }
    int excl = sm[t] - s + bsum[blockIdx.x];
#pragma unroll
    for (int j = 0; j < 16; j++) {
        int idx = base + j;
        if (idx < N_NODES) { int rp = excl + loc[j]; rowptr[idx] = rp; cursor[idx] = rp; }
    }
}

__global__ void build_csr(const int* __restrict__ src, const int* __restrict__ dst,
                          int* __restrict__ cursor, int* __restrict__ col) {
    int e = blockIdx.x * 256 + threadIdx.x;
    if (e < N_EDGES) {
        int d = dst[e];
        int p = atomicAdd(&cursor[d], 1);
        col[p] = src[e];
    }
}

// -------- XCD-sliced aggregation, layer 1: fp32 x -> bf16 out --------
// slice = blockIdx%8 (-> one XCD via round-robin dispatch); 16 feats/slice
// (64 B x 50K nodes = 3.2 MB, L2-resident). 16-lane group per node.
__global__ __launch_bounds__(256) void agg_x_sliced(const float* __restrict__ x,
                                                    const int* __restrict__ rowptr,
                                                    const int* __restrict__ col,
                                                    u16* __restrict__ outp) {
    int slice = blockIdx.x & 7;
    int nb    = blockIdx.x >> 3;
    int g = threadIdx.x >> 4, l = threadIdx.x & 15;
    int node = nb * 16 + g;                 // 3125*16 == N_NODES exactly
    int beg = rowptr[node], end = rowptr[node + 1];
    size_t fo = (size_t)slice * 16 + l;     // feature index within 128
    float a = x[(size_t)node * F_IN + fo];
    int e = beg;
    for (; e + 8 <= end; e += 8) {
        int s[8];
#pragma unroll
        for (int j = 0; j < 8; j++) s[j] = col[e + j];
        float v[8];
#pragma unroll
        for (int j = 0; j < 8; j++) v[j] = x[(size_t)s[j] * F_IN + fo];
#pragma unroll
        for (int j = 0; j < 8; j++) a += v[j];
    }
    for (; e < end; ++e) a += x[(size_t)col[e] * F_IN + fo];
    outp[(size_t)node * F_IN + fo] = f2bf(a);
}

// -------- XCD-sliced aggregation, 256-feat bf16 -> bf16, optional BN fold --------
// 32 feats/slice (64 B x 50K = 3.2 MB slice). out = sc*acc + (deg+1)*sh when FOLD.
template <bool FOLD>
__global__ __launch_bounds__(256) void agg_sliced(const u16* __restrict__ h,
                                                  const int* __restrict__ rowptr,
                                                  const int* __restrict__ col,
                                                  const float* __restrict__ scsh,
                                                  u16* __restrict__ outp) {
    int slice = blockIdx.x & 7;
    int nb    = blockIdx.x >> 3;
    int g = threadIdx.x >> 4, l = threadIdx.x & 15;
    int node = nb * 16 + g;
    int beg = rowptr[node], end = rowptr[node + 1];
    const u16x2* hp = reinterpret_cast<const u16x2*>(h);   // 128 units/row
    size_t uo = (size_t)slice * 16 + l;                    // u16x2 unit within row
    u16x2 sv = hp[(size_t)node * 128 + uo];
    float a0 = bf2f(sv[0]), a1 = bf2f(sv[1]);
    int e = beg;
    for (; e + 8 <= end; e += 8) {
        int s[8];
#pragma unroll
        for (int j = 0; j < 8; j++) s[j] = col[e + j];
        u16x2 v[8];
#pragma unroll
        for (int j = 0; j < 8; j++) v[j] = hp[(size_t)s[j] * 128 + uo];
#pragma unroll
        for (int j = 0; j < 8; j++) { a0 += bf2f(v[j][0]); a1 += bf2f(v[j][1]); }
    }
    for (; e < end; ++e) {
        u16x2 v = hp[(size_t)col[e] * 128 + uo];
        a0 += bf2f(v[0]); a1 += bf2f(v[1]);
    }
    if constexpr (FOLD) {
        int c = slice * 32 + l * 2;
        float2 sc = *reinterpret_cast<const float2*>(&scsh[c]);
        float2 sh = *reinterpret_cast<const float2*>(&scsh[HID + c]);
        float m = (float)(end - beg + 1);
        a0 = a0 * sc.x + m * sh.x;
        a1 = a1 * sc.y + m * sh.y;
    }
    u16x2 r; r[0] = f2bf(a0); r[1] = f2bf(a1);
    reinterpret_cast<u16x2*>(outp)[(size_t)node * 128 + uo] = r;
}

// ------- W pre-transpose + bf16 split, all 6 weights in one kernel -------
__global__ void wsplit_all(const float* __restrict__ w1a, const float* __restrict__ w2a,
                           const float* __restrict__ w1s, const float* __restrict__ w2s,
                           u16* __restrict__ th, u16* __restrict__ tl) {
    int idx = blockIdx.x * 256 + threadIdx.x;
    const float* W; int K; int local; size_t dof;
    if (idx < 32768)       { W = w1a;         K = 128; local = idx;          dof = 0; }
    else if (idx < 98304)  { W = w2a;         K = 256; local = idx - 32768;  dof = 32768; }
    else if (idx < 163840) { W = w1s;         K = 256; local = idx - 98304;  dof = 98304; }
    else if (idx < 229376) { W = w1s + 65536; K = 256; local = idx - 163840; dof = 163840; }
    else if (idx < 294912) { W = w2s;         K = 256; local = idx - 229376; dof = 229376; }
    else if (idx < 360448) { W = w2s + 65536; K = 256; local = idx - 294912; dof = 294912; }
    else return;
    int n = local & 255, k = local >> 8;
    float f = W[(size_t)k * 256 + n];
    u16 h = f2bf(f);
    th[dof + (size_t)n * K + k] = h;
    tl[dof + (size_t)n * K + k] = f2bf(f - bf2f(h));
}

// ------- MFMA GEMM: C[M][256] = bf16(relu(A[M][K] @ W + bias)), A bf16 -------
// Block 128 rows x 256 cols (in-place safe). 4 waves, each 64x128.
// acc += A*Whi + A*Wlo  (W fp32-grade; A carries bf16 storage rounding)
template <int K, bool STATS>
__global__ __launch_bounds__(256, 2) void gemm_mfma(const u16* __restrict__ A,
                                                    const u16* __restrict__ Wth,
                                                    const u16* __restrict__ Wtl,
                                                    const float* __restrict__ bias,
                                                    u16* __restrict__ C,
                                                    float* __restrict__ stats) {
    constexpr int BM = 128, BK = 32;
    __shared__ alignas(16) u16 Ah[BM * BK];
    __shared__ alignas(16) u16 Bh[HID * BK];
    __shared__ alignas(16) u16 Bl[HID * BK];
    __shared__ float smsum[HID];
    __shared__ float smsq[HID];

    const int tid  = threadIdx.x;
    const int r0   = blockIdx.x * BM;
    const int lane = tid & 63, wid = tid >> 6;
    const int wm = wid >> 1, wn = wid & 1;
    const int l15 = lane & 15, kg = lane >> 4;

    const int arow = tid >> 1, ahalf = tid & 1;
    const bool avalid = (r0 + arow) < N_NODES;
    const u16* aptr = A + (size_t)(r0 + arow) * K + ahalf * 16;
    const u16* bhptr = Wth + (size_t)tid * K;
    const u16* blptr = Wtl + (size_t)tid * K;

    f32x4 acc[4][8];
#pragma unroll
    for (int i = 0; i < 4; i++)
#pragma unroll
        for (int j = 0; j < 8; j++) acc[i][j] = (f32x4){0.f, 0.f, 0.f, 0.f};

    for (int k0 = 0; k0 < K; k0 += BK) {
        // ---- stage A tile (128 x 32 bf16, chunk-swizzled) ----
        u16x8 av[2];
        if (avalid) {
            av[0] = *reinterpret_cast<const u16x8*>(aptr + k0);
            av[1] = *reinterpret_cast<const u16x8*>(aptr + k0 + 8);
        } else {
            av[0] = (u16x8){0, 0, 0, 0, 0, 0, 0, 0};
            av[1] = av[0];
        }
#pragma unroll
        for (int j = 0; j < 2; j++) {
            int c = ahalf * 2 + j;
            int off = arow * 64 + ((c ^ ((arow >> 1) & 3)) << 4);
            *reinterpret_cast<u16x8*>((char*)Ah + off) = av[j];
        }
        // ---- stage B tile (Wt[n][k] hi/lo, n = tid, chunk-swizzled) ----
#pragma unroll
        for (int j = 0; j < 4; j++) {
            u16x8 v = *reinterpret_cast<const u16x8*>(bhptr + k0 + j * 8);
            int off = tid * 64 + ((j ^ ((tid >> 1) & 3)) << 4);
            *reinterpret_cast<u16x8*>((char*)Bh + off) = v;
        }
#pragma unroll
        for (int j = 0; j < 4; j++) {
            u16x8 v = *reinterpret_cast<const u16x8*>(blptr + k0 + j * 8);
            int off = tid * 64 + ((j ^ ((tid >> 1) & 3)) << 4);
            *reinterpret_cast<u16x8*>((char*)Bl + off) = v;
        }
        __syncthreads();
        // ---- MFMA: wave tile 64x128, 64 mfma per K-step ----
        bf16x8 ah[4];
#pragma unroll
        for (int mi = 0; mi < 4; mi++) {
            int r = wm * 64 + mi * 16 + l15;
            int off = r * 64 + ((kg ^ ((r >> 1) & 3)) << 4);
            ah[mi] = __builtin_bit_cast(bf16x8, *reinterpret_cast<const u16x8*>((const char*)Ah + off));
        }
#pragma unroll
        for (int ni = 0; ni < 8; ni++) {
            int n = wn * 128 + ni * 16 + l15;
            int off = n * 64 + ((kg ^ ((n >> 1) & 3)) << 4);
            bf16x8 bh = __builtin_bit_cast(bf16x8, *reinterpret_cast<const u16x8*>((const char*)Bh + off));
            bf16x8 bl = __builtin_bit_cast(bf16x8, *reinterpret_cast<const u16x8*>((const char*)Bl + off));
#pragma unroll
            for (int mi = 0; mi < 4; mi++) {
                acc[mi][ni] = __builtin_amdgcn_mfma_f32_16x16x32_bf16(ah[mi], bh, acc[mi][ni], 0, 0, 0);
                acc[mi][ni] = __builtin_amdgcn_mfma_f32_16x16x32_bf16(ah[mi], bl, acc[mi][ni], 0, 0, 0);
            }
        }
        __syncthreads();
    }
    // ---- epilogue: bias + relu + bf16 store; optional per-column stats ----
    if constexpr (STATS) {
        smsum[tid] = 0.f;
        smsq[tid]  = 0.f;
        __syncthreads();
    }
    float bv[8];
#pragma unroll
    for (int ni = 0; ni < 8; ni++) bv[ni] = bias[wn * 128 + ni * 16 + l15];
    float ps[8] = {}, pq[8] = {};
#pragma unroll
    for (int mi = 0; mi < 4; mi++) {
        int rowb = r0 + wm * 64 + mi * 16 + kg * 4;
#pragma unroll
        for (int rr = 0; rr < 4; rr++) {
            int row = rowb + rr;
            if (row < N_NODES) {
                u16* cp = C + (size_t)row * HID + wn * 128 + l15;
#pragma unroll
                for (int ni = 0; ni < 8; ni++) {
                    float v = fmaxf(acc[mi][ni][rr] + bv[ni], 0.f);
                    cp[ni * 16] = f2bf(v);
                    if constexpr (STATS) { ps[ni] += v; pq[ni] += v * v; }
                }
            }
        }
    }
    if constexpr (STATS) {
#pragma unroll
        for (int ni = 0; ni < 8; ni++) {
            int c = wn * 128 + ni * 16 + l15;
            atomicAdd(&smsum[c], ps[ni]);
            atomicAdd(&smsq[c], pq[ni]);
        }
        __syncthreads();
        atomicAdd(&stats[tid], smsum[tid]);
        atomicAdd(&stats[HID + tid], smsq[tid]);
    }
}

// ---------------- BN finalize: stats -> scale/shift ----------------
__global__ void bn_finalize(const float* __restrict__ stats, const float* __restrict__ gamma,
                            const float* __restrict__ beta, float* __restrict__ scsh) {
    int c = threadIdx.x;
    float mu  = stats[c] * (1.f / N_NODES);
    float var = stats[HID + c] * (1.f / N_NODES) - mu * mu;
    float g = gamma[c] * rsqrtf(var + BN_EPS);
    scsh[c] = g;
    scsh[HID + c] = beta[c] - mu * g;
}

// ---------------- mean pool (batch sorted), layer-3 BN folded ----------------
__device__ __forceinline__ int lowerb(const int* a, int key) {
    int lo = 0, hi = N_NODES;
    while (lo < hi) { int mid = (lo + hi) >> 1; if (a[mid] < key) lo = mid + 1; else hi = mid; }
    return lo;
}

__global__ void pool_k(const u16* __restrict__ h, const int* __restrict__ batch,
                       const float* __restrict__ scsh, float* __restrict__ out) {
    __shared__ int bnd[2];
    int g = blockIdx.x;
    if (threadIdx.x == 0) bnd[0] = lowerb(batch, g);
    if (threadIdx.x == 1) bnd[1] = lowerb(batch, g + 1);
    __syncthreads();
    int lo = bnd[0], hi = bnd[1];
    int c = threadIdx.x;
    float s = 0.f;
    for (int r = lo; r < hi; ++r) s += bf2f(h[(size_t)r * HID + c]);
    int cnt = hi - lo;
    float v = (cnt > 0) ? (scsh[c] * (s / (float)cnt) + scsh[HID + c]) : 0.f;
    out[(size_t)g * HID + c] = v;
}

// ---------------- launch ----------------
extern "C" void kernel_launch(void* const* d_in, const int* in_sizes, int n_in,
                              void* d_out, int out_size, void* d_ws, size_t ws_size,
                              hipStream_t stream) {
    const float* x   = (const float*)d_in[0];
    const int*   ei  = (const int*)d_in[1];
    const int* batch = (const int*)d_in[2];
    const float* w1a = (const float*)d_in[3];
    const float* b1a = (const float*)d_in[4];
    const float* w2a = (const float*)d_in[5];
    const float* b2a = (const float*)d_in[6];
    const float* ga  = (const float*)d_in[7];
    const float* ba  = (const float*)d_in[8];
    const float* w1s = (const float*)d_in[9];
    const float* b1s = (const float*)d_in[10];
    const float* w2s = (const float*)d_in[11];
    const float* b2s = (const float*)d_in[12];
    const float* gs  = (const float*)d_in[13];
    const float* bs  = (const float*)d_in[14];
    const int* src = ei;
    const int* dst = ei + N_EDGES;

    char* ws = (char*)d_ws;
    size_t off = 0;
    auto alloc = [&](size_t bytes) { void* p = ws + off; off += (bytes + 255) & ~(size_t)255; return p; };
    u16* A      = (u16*)alloc(sizeof(u16) * (size_t)N_NODES * HID);
    u16* B      = (u16*)alloc(sizeof(u16) * (size_t)N_NODES * HID);
    int* rowptr = (int*)alloc(sizeof(int) * (N_NODES + 1));
    int* deg    = (int*)alloc(sizeof(int) * N_NODES);
    int* cursor = (int*)alloc(sizeof(int) * N_NODES);
    int* col    = (int*)alloc(sizeof(int) * N_EDGES);
    int* bsum   = (int*)alloc(sizeof(int) * 64);
    float* stats  = (float*)alloc(sizeof(float) * 512 * 3);  // sum||sq per layer
    float* scsh   = (float*)alloc(sizeof(float) * 512 * 3);  // scale||shift per layer
    constexpr size_t WT_TOT = 32768 + 5 * 65536;
    u16* WtH = (u16*)alloc(sizeof(u16) * WT_TOT);
    u16* WtL = (u16*)alloc(sizeof(u16) * WT_TOT);
    constexpr size_t o1a = 0, o2a = 32768, o1s0 = 98304, o1s1 = 163840, o2s0 = 229376, o2s1 = 294912;
    float* out    = (float*)d_out;
    (void)ws_size; (void)in_sizes; (void)n_in; (void)out_size;

    // ---- weight prep ----
    wsplit_all<<<(360448 + 255) / 256, 256, 0, stream>>>(w1a, w2a, w1s, w2s, WtH, WtL);
    hipMemsetAsync(stats, 0, sizeof(float) * 512 * 3, stream);

    // ---- CSR build (by dst) ----
    hipMemsetAsync(deg, 0, sizeof(int) * N_NODES, stream);
    hist_k<<<N_EDGES / 256, 256, 0, stream>>>(dst, deg);
    scan_part1<<<SCAN_NB, 256, 0, stream>>>(deg, bsum);
    scan_tops<<<1, 64, 0, stream>>>(bsum, rowptr);
    scan_final<<<SCAN_NB, 256, 0, stream>>>(deg, bsum, rowptr, cursor);
    build_csr<<<N_EDGES / 256, 256, 0, stream>>>(src, dst, cursor, col);

    const int AGG_GRID  = 8 * (N_NODES / 16);    // 8 slices x 3125 node-blocks
    const int GEMM_GRID = (N_NODES + 127) / 128; // 391

    // ---- layer 1 (gather fp32 x directly, 16-feat slices) ----
    agg_x_sliced<<<AGG_GRID, 256, 0, stream>>>(x, rowptr, col, A);
    gemm_mfma<128, false><<<GEMM_GRID, 256, 0, stream>>>(A, WtH + o1a, WtL + o1a, b1a, B, nullptr);
    gemm_mfma<256, true><<<GEMM_GRID, 256, 0, stream>>>(B, WtH + o2a, WtL + o2a, b2a, B, stats);
    bn_finalize<<<1, 256, 0, stream>>>(stats, ga, ba, scsh);

    // ---- layer 2 (BN1 folded into aggregate) ----
    agg_sliced<true><<<AGG_GRID, 256, 0, stream>>>(B, rowptr, col, scsh, A);
    gemm_mfma<256, false><<<GEMM_GRID, 256, 0, stream>>>(A, WtH + o1s0, WtL + o1s0, b1s, A, nullptr);
    gemm_mfma<256, true><<<GEMM_GRID, 256, 0, stream>>>(A, WtH + o2s0, WtL + o2s0, b2s, A, stats + 512);
    bn_finalize<<<1, 256, 0, stream>>>(stats + 512, gs, bs, scsh + 512);

    // ---- layer 3 (BN2 folded into aggregate) ----
    agg_sliced<true><<<AGG_GRID, 256, 0, stream>>>(A, rowptr, col, scsh + 512, B);
    gemm_mfma<256, false><<<GEMM_GRID, 256, 0, stream>>>(B, WtH + o1s1, WtL + o1s1, b1s + 256, B, nullptr);
    gemm_mfma<256, true><<<GEMM_GRID, 256, 0, stream>>>(B, WtH + o2s1, WtL + o2s1, b2s + 256, B, stats + 1024);
    bn_finalize<<<1, 256, 0, stream>>>(stats + 1024, gs + 256, bs + 256, scsh + 1024);

    // ---- pool (BN3 folded in) ----
    pool_k<<<N_GRAPHS, 256, 0, stream>>>(B, batch, scsh + 1024, out);
}

// Round 8
// 464.719 us; speedup vs baseline: 1.4430x; 1.3403x over previous
//
#include <hip/hip_runtime.h>
#include <cstdint>
#include <cstddef>

// GIN 3-layer + BN + mean-pool. R8 = R7 with the global_load_lds W-source fix:
// source address must be PER-LANE (+ lane*16); R7 passed a wave-uniform source
// so all lanes replicated the same 16B. A staging was already per-lane.

constexpr int N_NODES  = 50000;
constexpr int N_EDGES  = 800000;
constexpr int F_IN     = 128;
constexpr int HID      = 256;
constexpr int N_GRAPHS = 512;
constexpr float BN_EPS = 1e-5f;

constexpr int SCAN_CHUNK = 4096;
constexpr int SCAN_NB    = (N_NODES + SCAN_CHUNK - 1) / SCAN_CHUNK; // 13

typedef unsigned short u16;
typedef u16 u16x2 __attribute__((ext_vector_type(2)));
typedef u16 u16x4 __attribute__((ext_vector_type(4)));
typedef u16 u16x8 __attribute__((ext_vector_type(8)));
typedef __bf16 bf16x8 __attribute__((ext_vector_type(8)));
typedef float f32x4 __attribute__((ext_vector_type(4)));

__device__ __forceinline__ u16 f2bf(float f) {
    uint32_t u = __float_as_uint(f);
    uint32_t r = (u + 0x7FFFu + ((u >> 16) & 1u)) >> 16;
    return (u16)r;
}
__device__ __forceinline__ float bf2f(u16 h) {
    return __uint_as_float(((uint32_t)h) << 16);
}

// async global->LDS, 16B per lane; LDS dest = wave-uniform base + lane*16,
// global source = PER-LANE address (must include the lane offset!)
__device__ __forceinline__ void gload16(const void* g, void* l) {
    __builtin_amdgcn_global_load_lds(
        (const __attribute__((address_space(1))) uint32_t*)g,
        (__attribute__((address_space(3))) uint32_t*)l, 16, 0, 0);
}

// ---------------- x -> bf16 ----------------
__global__ void f2bf_k(const float* __restrict__ in, u16* __restrict__ outp, int n8) {
    int i = blockIdx.x * 256 + threadIdx.x;
    if (i >= n8) return;
    float4 a = reinterpret_cast<const float4*>(in)[i * 2];
    float4 b = reinterpret_cast<const float4*>(in)[i * 2 + 1];
    u16x8 v;
    v[0] = f2bf(a.x); v[1] = f2bf(a.y); v[2] = f2bf(a.z); v[3] = f2bf(a.w);
    v[4] = f2bf(b.x); v[5] = f2bf(b.y); v[6] = f2bf(b.z); v[7] = f2bf(b.w);
    reinterpret_cast<u16x8*>(outp)[i] = v;
}

// ---------------- CSR build ----------------
__global__ void hist_k(const int* __restrict__ dst, int* __restrict__ deg) {
    int e = blockIdx.x * 256 + threadIdx.x;
    if (e < N_EDGES) atomicAdd(&deg[dst[e]], 1);
}

__global__ void scan_part1(const int* __restrict__ in, int* __restrict__ bsum) {
    __shared__ int sm[256];
    int t = threadIdx.x;
    int base = blockIdx.x * SCAN_CHUNK + t * 16;
    int s = 0;
#pragma unroll
    for (int j = 0; j < 16; j++) { int idx = base + j; s += (idx < N_NODES) ? in[idx] : 0; }
    sm[t] = s; __syncthreads();
    for (int off = 128; off > 0; off >>= 1) {
        if (t < off) sm[t] += sm[t + off];
        __syncthreads();
    }
    if (t == 0) bsum[blockIdx.x] = sm[0];
}

__global__ void scan_tops(int* __restrict__ bsum, int* __restrict__ rowptr) {
    if (threadIdx.x == 0 && blockIdx.x == 0) {
        int acc = 0;
        for (int i = 0; i < SCAN_NB; i++) { int v = bsum[i]; bsum[i] = acc; acc += v; }
        rowptr[N_NODES] = acc; // == N_EDGES
    }
}

__global__ void scan_final(const int* __restrict__ in, const int* __restrict__ bsum,
                           int* __restrict__ rowptr, int* __restrict__ cursor) {
    __shared__ int sm[256];
    int t = threadIdx.x;
    int base = blockIdx.x * SCAN_CHUNK + t * 16;
    int loc[16]; int s = 0;
#pragma unroll
    for (int j = 0; j < 16; j++) { int idx = base + j; loc[j] = s; s += (idx < N_NODES) ? in[idx] : 0; }
    sm[t] = s; __syncthreads();
    for (int off = 1; off < 256; off <<= 1) {
        int v = (t >= off) ? sm[t - off] : 0;
        __syncthreads();
        sm[t] += v;
        __syncthreads();
    }
    int excl = sm[t] - s + bsum[blockIdx.x];
#pragma unroll
    for (int j = 0; j < 16; j++) {
        int idx = base + j;
        if (idx < N_NODES) { int rp = excl + loc[j]; rowptr[idx] = rp; cursor[idx] = rp; }
    }
}

__global__ void build_csr(const int* __restrict__ src, const int* __restrict__ dst,
                          int* __restrict__ cursor, int* __restrict__ col) {
    int e = blockIdx.x * 256 + threadIdx.x;
    if (e < N_EDGES) {
        int d = dst[e];
        int p = atomicAdd(&cursor[d], 1);
        col[p] = src[e];
    }
}

// -------- aggregation (bf16 in/out, fp32 accum), BN fold computed inline --------
// out[n] = fold( h[n] + sum_{e: dst=n} h[src[e]] );  fold: sc*acc + (deg+1)*sh
template <int F, bool FOLD>
__global__ __launch_bounds__(256) void aggregate_k(const u16* __restrict__ h,
                                                   const int* __restrict__ rowptr,
                                                   const int* __restrict__ col,
                                                   const float* __restrict__ stats,
                                                   const float* __restrict__ gamma,
                                                   const float* __restrict__ beta,
                                                   u16* __restrict__ outp) {
    int node = blockIdx.x * 4 + (threadIdx.x >> 6);
    if (node >= N_NODES) return;
    int lane = threadIdx.x & 63;
    int beg = rowptr[node], end = rowptr[node + 1];
    if constexpr (F == 256) {
        float sc[4], sh[4];
        if constexpr (FOLD) {
            int c4 = lane * 4;
#pragma unroll
            for (int i = 0; i < 4; i++) {
                float mu  = stats[c4 + i] * (1.f / N_NODES);
                float var = stats[HID + c4 + i] * (1.f / N_NODES) - mu * mu;
                float g = gamma[c4 + i] * rsqrtf(var + BN_EPS);
                sc[i] = g;
                sh[i] = beta[c4 + i] - mu * g;
            }
        }
        const u16x4* hp = reinterpret_cast<const u16x4*>(h); // row stride 64
        u16x4 sv = hp[(size_t)node * 64 + lane];
        float acc[4] = {bf2f(sv[0]), bf2f(sv[1]), bf2f(sv[2]), bf2f(sv[3])};
        int e = beg;
        for (; e + 4 <= end; e += 4) {
            int s0 = col[e], s1 = col[e + 1], s2 = col[e + 2], s3 = col[e + 3];
            u16x4 v0 = hp[(size_t)s0 * 64 + lane];
            u16x4 v1 = hp[(size_t)s1 * 64 + lane];
            u16x4 v2 = hp[(size_t)s2 * 64 + lane];
            u16x4 v3 = hp[(size_t)s3 * 64 + lane];
#pragma unroll
            for (int i = 0; i < 4; i++)
                acc[i] += (bf2f(v0[i]) + bf2f(v1[i])) + (bf2f(v2[i]) + bf2f(v3[i]));
        }
        for (; e < end; ++e) {
            int s = col[e];
            u16x4 v = hp[(size_t)s * 64 + lane];
#pragma unroll
            for (int i = 0; i < 4; i++) acc[i] += bf2f(v[i]);
        }
        if constexpr (FOLD) {
            float m = (float)(end - beg + 1);
#pragma unroll
            for (int i = 0; i < 4; i++) acc[i] = acc[i] * sc[i] + m * sh[i];
        }
        u16x4 r;
#pragma unroll
        for (int i = 0; i < 4; i++) r[i] = f2bf(acc[i]);
        reinterpret_cast<u16x4*>(outp)[(size_t)node * 64 + lane] = r;
    } else { // F == 128, no fold (layer-1 input)
        const u16x2* hp = reinterpret_cast<const u16x2*>(h); // row stride 64
        u16x2 sv = hp[(size_t)node * 64 + lane];
        float acc[2] = {bf2f(sv[0]), bf2f(sv[1])};
        int e = beg;
        for (; e + 4 <= end; e += 4) {
            int s0 = col[e], s1 = col[e + 1], s2 = col[e + 2], s3 = col[e + 3];
            u16x2 v0 = hp[(size_t)s0 * 64 + lane];
            u16x2 v1 = hp[(size_t)s1 * 64 + lane];
            u16x2 v2 = hp[(size_t)s2 * 64 + lane];
            u16x2 v3 = hp[(size_t)s3 * 64 + lane];
#pragma unroll
            for (int i = 0; i < 2; i++)
                acc[i] += (bf2f(v0[i]) + bf2f(v1[i])) + (bf2f(v2[i]) + bf2f(v3[i]));
        }
        for (; e < end; ++e) {
            int s = col[e];
            u16x2 v = hp[(size_t)s * 64 + lane];
#pragma unroll
            for (int i = 0; i < 2; i++) acc[i] += bf2f(v[i]);
        }
        u16x2 r;
        r[0] = f2bf(acc[0]); r[1] = f2bf(acc[1]);
        reinterpret_cast<u16x2*>(outp)[(size_t)node * 64 + lane] = r;
    }
}

// ------- W pre-transpose + bf16 split -> pre-swizzled LDS-image layout -------
// For K-step tile t, the 16KB image is [256 n][4 units uo][8 elems], with
// uo = j ^ ((n>>1)&3) where j = k-unit within the 32-k tile. Staging in the
// GEMM is then a pure linear global_load_lds copy.
__global__ void wsplit_all(const float* __restrict__ w1a, const float* __restrict__ w2a,
                           const float* __restrict__ w1s, const float* __restrict__ w2s,
                           u16* __restrict__ th, u16* __restrict__ tl) {
    int idx = blockIdx.x * 256 + threadIdx.x;
    const float* W; int local; size_t dof;
    if (idx < 32768)       { W = w1a;         local = idx;          dof = 0; }
    else if (idx < 98304)  { W = w2a;         local = idx - 32768;  dof = 32768; }
    else if (idx < 163840) { W = w1s;         local = idx - 98304;  dof = 98304; }
    else if (idx < 229376) { W = w1s + 65536; local = idx - 163840; dof = 163840; }
    else if (idx < 294912) { W = w2s;         local = idx - 229376; dof = 229376; }
    else if (idx < 360448) { W = w2s + 65536; local = idx - 294912; dof = 294912; }
    else return;
    int n = local & 255, k = local >> 8;
    float f = W[(size_t)k * 256 + n];
    u16 h = f2bf(f);
    int t = k >> 5, j = (k >> 3) & 3, e = k & 7;
    int uo = j ^ ((n >> 1) & 3);
    size_t di = dof + (size_t)t * 8192 + n * 32 + uo * 8 + e;
    th[di] = h;
    tl[di] = f2bf(f - bf2f(h));
}

// ------- MFMA GEMM: C[M][256] = bf16(relu(A[M][K] @ W + bias)), A bf16 -------
// Block 128 rows x 256 cols (full row -> in-place safe). 4 waves, each 64x128.
// Staging via global_load_lds: W tiles are linear copies of the pre-swizzled
// image; A uses pre-swizzled per-lane global source (m173 pattern).
template <int K, bool STATS>
__global__ __launch_bounds__(256, 2) void gemm_mfma(const u16* __restrict__ A,
                                                    const u16* __restrict__ Wth,
                                                    const u16* __restrict__ Wtl,
                                                    const float* __restrict__ bias,
                                                    u16* __restrict__ C,
                                                    float* __restrict__ stats) {
    constexpr int BM = 128, BK = 32;
    __shared__ alignas(16) u16 Ah[BM * BK];     // 8 KB
    __shared__ alignas(16) u16 Bh[HID * BK];    // 16 KB
    __shared__ alignas(16) u16 Bl[HID * BK];    // 16 KB
    __shared__ float smsum[HID];
    __shared__ float smsq[HID];

    const int tid  = threadIdx.x;
    const int r0   = blockIdx.x * BM;
    const int lane = tid & 63, wv = tid >> 6;
    const int wm = wv >> 1, wn = wv & 1;
    const int l15 = lane & 15, kg = lane >> 4;

    // A staging source precompute (2 chunks/wave, 1KB each):
    // chunk p covers linear LDS units nu = wv*128 + p*64 + lane
    int aro[2], aco[2];
#pragma unroll
    for (int p = 0; p < 2; p++) {
        int nu = wv * 128 + p * 64 + lane;
        int r = nu >> 2, us = nu & 3;
        int u = us ^ ((r >> 1) & 3);
        aro[p] = r;           // row within tile
        aco[p] = u * 8;       // k offset within 32-k step
    }

    f32x4 acc[4][8];
#pragma unroll
    for (int i = 0; i < 4; i++)
#pragma unroll
        for (int j = 0; j < 8; j++) acc[i][j] = (f32x4){0.f, 0.f, 0.f, 0.f};

    for (int k0 = 0; k0 < K; k0 += BK) {
        int t = k0 >> 5;
        // ---- stage A (8 KB): per-lane pre-swizzled source, linear LDS dest ----
#pragma unroll
        for (int p = 0; p < 2; p++) {
            const u16* src = A + (size_t)(r0 + aro[p]) * K + k0 + aco[p];
            gload16(src, (char*)Ah + (size_t)(wv * 2 + p) * 1024);
        }
        // ---- stage W hi/lo (16 KB each): linear image copy, PER-LANE source ----
        const char* wh = (const char*)Wth + (size_t)t * 16384 + (size_t)wv * 4096 + (size_t)lane * 16;
        const char* wl = (const char*)Wtl + (size_t)t * 16384 + (size_t)wv * 4096 + (size_t)lane * 16;
#pragma unroll
        for (int c = 0; c < 4; c++) {
            gload16(wh + c * 1024, (char*)Bh + (size_t)wv * 4096 + c * 1024);
            gload16(wl + c * 1024, (char*)Bl + (size_t)wv * 4096 + c * 1024);
        }
        __syncthreads();
        // ---- MFMA: wave tile 64x128, 64 mfma per K-step ----
        bf16x8 ah[4];
#pragma unroll
        for (int mi = 0; mi < 4; mi++) {
            int r = wm * 64 + mi * 16 + l15;
            int off = r * 64 + ((kg ^ ((r >> 1) & 3)) << 4);
            ah[mi] = __builtin_bit_cast(bf16x8, *reinterpret_cast<const u16x8*>((const char*)Ah + off));
        }
#pragma unroll
        for (int ni = 0; ni < 8; ni++) {
            int n = wn * 128 + ni * 16 + l15;
            int off = n * 64 + ((kg ^ ((n >> 1) & 3)) << 4);
            bf16x8 bh = __builtin_bit_cast(bf16x8, *reinterpret_cast<const u16x8*>((const char*)Bh + off));
            bf16x8 bl = __builtin_bit_cast(bf16x8, *reinterpret_cast<const u16x8*>((const char*)Bl + off));
#pragma unroll
            for (int mi = 0; mi < 4; mi++) {
                acc[mi][ni] = __builtin_amdgcn_mfma_f32_16x16x32_bf16(ah[mi], bh, acc[mi][ni], 0, 0, 0);
                acc[mi][ni] = __builtin_amdgcn_mfma_f32_16x16x32_bf16(ah[mi], bl, acc[mi][ni], 0, 0, 0);
            }
        }
        __syncthreads();
    }
    // ---- epilogue: bias + relu + bf16 store; optional per-column stats ----
    if constexpr (STATS) {
        smsum[tid] = 0.f;
        smsq[tid]  = 0.f;
        __syncthreads();
    }
    float bv[8];
#pragma unroll
    for (int ni = 0; ni < 8; ni++) bv[ni] = bias[wn * 128 + ni * 16 + l15];
    float ps[8] = {}, pq[8] = {};
#pragma unroll
    for (int mi = 0; mi < 4; mi++) {
        int rowb = r0 + wm * 64 + mi * 16 + kg * 4;
#pragma unroll
        for (int rr = 0; rr < 4; rr++) {
            int row = rowb + rr;
            if (row < N_NODES) {
                u16* cp = C + (size_t)row * HID + wn * 128 + l15;
#pragma unroll
                for (int ni = 0; ni < 8; ni++) {
                    float v = fmaxf(acc[mi][ni][rr] + bv[ni], 0.f);
                    cp[ni * 16] = f2bf(v);
                    if constexpr (STATS) { ps[ni] += v; pq[ni] += v * v; }
                }
            }
        }
    }
    if constexpr (STATS) {
#pragma unroll
        for (int ni = 0; ni < 8; ni++) {
            int c = wn * 128 + ni * 16 + l15;
            atomicAdd(&smsum[c], ps[ni]);
            atomicAdd(&smsq[c], pq[ni]);
        }
        __syncthreads();
        atomicAdd(&stats[tid], smsum[tid]);
        atomicAdd(&stats[HID + tid], smsq[tid]);
    }
}

// ---------------- mean pool (batch sorted), layer-3 BN computed inline ----------------
__device__ __forceinline__ int lowerb(const int* a, int key) {
    int lo = 0, hi = N_NODES;
    while (lo < hi) { int mid = (lo + hi) >> 1; if (a[mid] < key) lo = mid + 1; else hi = mid; }
    return lo;
}

__global__ void pool_k(const u16* __restrict__ h, const int* __restrict__ batch,
                       const float* __restrict__ stats, const float* __restrict__ gamma,
                       const float* __restrict__ beta, float* __restrict__ out) {
    __shared__ int bnd[2];
    int g = blockIdx.x;
    if (threadIdx.x == 0) bnd[0] = lowerb(batch, g);
    if (threadIdx.x == 1) bnd[1] = lowerb(batch, g + 1);
    __syncthreads();
    int lo = bnd[0], hi = bnd[1];
    int c = threadIdx.x;
    float mu  = stats[c] * (1.f / N_NODES);
    float var = stats[HID + c] * (1.f / N_NODES) - mu * mu;
    float sc = gamma[c] * rsqrtf(var + BN_EPS);
    float sh = beta[c] - mu * sc;
    float s = 0.f;
    for (int r = lo; r < hi; ++r) s += bf2f(h[(size_t)r * HID + c]);
    int cnt = hi - lo;
    float v = (cnt > 0) ? (sc * (s / (float)cnt) + sh) : 0.f;
    out[(size_t)g * HID + c] = v;
}

// ---------------- launch ----------------
extern "C" void kernel_launch(void* const* d_in, const int* in_sizes, int n_in,
                              void* d_out, int out_size, void* d_ws, size_t ws_size,
                              hipStream_t stream) {
    const float* x   = (const float*)d_in[0];
    const int*   ei  = (const int*)d_in[1];
    const int* batch = (const int*)d_in[2];
    const float* w1a = (const float*)d_in[3];
    const float* b1a = (const float*)d_in[4];
    const float* w2a = (const float*)d_in[5];
    const float* b2a = (const float*)d_in[6];
    const float* ga  = (const float*)d_in[7];
    const float* ba  = (const float*)d_in[8];
    const float* w1s = (const float*)d_in[9];
    const float* b1s = (const float*)d_in[10];
    const float* w2s = (const float*)d_in[11];
    const float* b2s = (const float*)d_in[12];
    const float* gs  = (const float*)d_in[13];
    const float* bs  = (const float*)d_in[14];
    const int* src = ei;
    const int* dst = ei + N_EDGES;

    char* ws = (char*)d_ws;
    size_t off = 0;
    auto alloc = [&](size_t bytes) { void* p = ws + off; off += (bytes + 255) & ~(size_t)255; return p; };
    u16* A      = (u16*)alloc(sizeof(u16) * (size_t)N_NODES * HID);
    u16* B      = (u16*)alloc(sizeof(u16) * (size_t)N_NODES * HID);
    u16* Xb     = (u16*)alloc(sizeof(u16) * (size_t)N_NODES * F_IN);
    int* rowptr = (int*)alloc(sizeof(int) * (N_NODES + 1));
    int* deg    = (int*)alloc(sizeof(int) * N_NODES);
    int* cursor = (int*)alloc(sizeof(int) * N_NODES);
    int* col    = (int*)alloc(sizeof(int) * N_EDGES);
    int* bsum   = (int*)alloc(sizeof(int) * 64);
    float* stats  = (float*)alloc(sizeof(float) * 512 * 3);  // sum||sq per layer
    constexpr size_t WT_TOT = 32768 + 5 * 65536;
    u16* WtH = (u16*)alloc(sizeof(u16) * WT_TOT);
    u16* WtL = (u16*)alloc(sizeof(u16) * WT_TOT);
    constexpr size_t o1a = 0, o2a = 32768, o1s0 = 98304, o1s1 = 163840, o2s0 = 229376, o2s1 = 294912;
    float* out    = (float*)d_out;
    (void)ws_size; (void)in_sizes; (void)n_in; (void)out_size;

    // ---- input/weight prep ----
    f2bf_k<<<(N_NODES * F_IN / 8 + 255) / 256, 256, 0, stream>>>(x, Xb, N_NODES * F_IN / 8);
    wsplit_all<<<(360448 + 255) / 256, 256, 0, stream>>>(w1a, w2a, w1s, w2s, WtH, WtL);
    hipMemsetAsync(stats, 0, sizeof(float) * 512 * 3, stream);

    // ---- CSR build (by dst) ----
    hipMemsetAsync(deg, 0, sizeof(int) * N_NODES, stream);
    hist_k<<<N_EDGES / 256, 256, 0, stream>>>(dst, deg);
    scan_part1<<<SCAN_NB, 256, 0, stream>>>(deg, bsum);
    scan_tops<<<1, 64, 0, stream>>>(bsum, rowptr);
    scan_final<<<SCAN_NB, 256, 0, stream>>>(deg, bsum, rowptr, cursor);
    build_csr<<<N_EDGES / 256, 256, 0, stream>>>(src, dst, cursor, col);

    const int AGG_GRID  = (N_NODES + 3) / 4;     // 12500
    const int GEMM_GRID = (N_NODES + 127) / 128; // 391

    // ---- layer 1 ----
    aggregate_k<128, false><<<AGG_GRID, 256, 0, stream>>>(Xb, rowptr, col, nullptr, nullptr, nullptr, A);
    gemm_mfma<128, false><<<GEMM_GRID, 256, 0, stream>>>(A, WtH + o1a, WtL + o1a, b1a, B, nullptr);
    gemm_mfma<256, true><<<GEMM_GRID, 256, 0, stream>>>(B, WtH + o2a, WtL + o2a, b2a, B, stats);

    // ---- layer 2 (BN1 folded into aggregate, scale/shift inline) ----
    aggregate_k<256, true><<<AGG_GRID, 256, 0, stream>>>(B, rowptr, col, stats, ga, ba, A);
    gemm_mfma<256, false><<<GEMM_GRID, 256, 0, stream>>>(A, WtH + o1s0, WtL + o1s0, b1s, A, nullptr);
    gemm_mfma<256, true><<<GEMM_GRID, 256, 0, stream>>>(A, WtH + o2s0, WtL + o2s0, b2s, A, stats + 512);

    // ---- layer 3 (BN2 folded into aggregate) ----
    aggregate_k<256, true><<<AGG_GRID, 256, 0, stream>>>(A, rowptr, col, stats + 512, gs, bs, B);
    gemm_mfma<256, false><<<GEMM_GRID, 256, 0, stream>>>(B, WtH + o1s1, WtL + o1s1, b1s + 256, B, nullptr);
    gemm_mfma<256, true><<<GEMM_GRID, 256, 0, stream>>>(B, WtH + o2s1, WtL + o2s1, b2s + 256, B, stats + 1024);

    // ---- pool (BN3 inline) ----
    pool_k<<<N_GRAPHS, 256, 0, stream>>>(B, batch, stats + 1024, gs + 256, bs + 256, out);
}